// Round 1
// baseline (262.826 us; speedup 1.0000x reference)
//
#include <hip/hip_runtime.h>

// Problem constants (from setup_inputs)
#define V_    50000
#define D_    128
#define HOPS_ 3
#define B_    16
#define LC_   256
#define MC_   8
#define LK_   512
#define MK_   8

typedef __bf16  bf16x8  __attribute__((ext_vector_type(8)));
typedef unsigned short ushort8 __attribute__((ext_vector_type(8)));
typedef float   floatx4 __attribute__((ext_vector_type(4)));

__device__ inline unsigned short f2bf(float f) {
    union { float f; unsigned u; } x; x.f = f;
    unsigned r = x.u + 0x7FFFu + ((x.u >> 16) & 1u);   // RNE
    return (unsigned short)(r >> 16);
}

__device__ inline floatx4 mfma_bf16(ushort8 a, ushort8 b, floatx4 c) {
    return __builtin_amdgcn_mfma_f32_16x16x32_bf16(
        __builtin_bit_cast(bf16x8, a), __builtin_bit_cast(bf16x8, b), c, 0, 0, 0);
}

// ---------------------------------------------------------------------------
// Kernel 1: embedding-bag gathers.
//   blocks [0,384):   kf tiles  (hop,b,ktile of 64 rows)  + transposed copy
//   blocks [384,576): cf tiles  (hop,b,ltile of 64 rows)
// Each block: 64 rows x 128 d; thread owns (row = tid>>2, quarter = tid&3).
// ---------------------------------------------------------------------------
__global__ __launch_bounds__(256) void gather_kernel(
    const int* __restrict__ conv_seqs, const int* __restrict__ kb_arr,
    const float* __restrict__ Ct, const float* __restrict__ Kt,
    unsigned short* __restrict__ kf, unsigned short* __restrict__ kfT,
    unsigned short* __restrict__ cf)
{
    __shared__ float tile[64][132];          // +4 pad: conflict-free transpose

    const int tid = threadIdx.x;
    const int r   = tid >> 2;                // row in tile
    const int q   = tid & 3;                 // d-quarter
    const int d0  = q * 32;
    const int bx  = blockIdx.x;

    const int*   idxp;
    const float* table;
    unsigned short* dst;
    bool do_transpose;
    int hop, b, row0;

    if (bx < HOPS_ * B_ * (LK_ / 64)) {      // 384 kf blocks
        hop  = bx / (B_ * 8);
        int rem = bx % (B_ * 8);
        b    = rem >> 3;
        row0 = (rem & 7) * 64;
        idxp  = kb_arr + (size_t)(b * LK_ + row0 + r) * MK_;
        table = Kt + (size_t)hop * V_ * D_;
        dst   = kf + (((size_t)(hop * B_ + b) * LK_) + row0 + r) * D_ + d0;
        do_transpose = true;
    } else {                                  // 192 cf blocks
        int id = bx - HOPS_ * B_ * (LK_ / 64);
        hop  = id / (B_ * 4);
        int rem = id % (B_ * 4);
        b    = rem >> 2;
        row0 = (rem & 3) * 64;
        idxp  = conv_seqs + (size_t)(b * LC_ + row0 + r) * MC_;
        table = Ct + (size_t)hop * V_ * D_;
        dst   = cf + (((size_t)(hop * B_ + b) * LC_) + row0 + r) * D_ + d0;
        do_transpose = false;
    }

    float4 acc[8];
    #pragma unroll
    for (int j = 0; j < 8; ++j) acc[j] = make_float4(0.f, 0.f, 0.f, 0.f);

    #pragma unroll
    for (int m = 0; m < 8; ++m) {
        int idx = idxp[m];
        const float4* src = (const float4*)(table + (size_t)idx * D_ + d0);
        #pragma unroll
        for (int j = 0; j < 8; ++j) {
            float4 v = src[j];
            acc[j].x += v.x; acc[j].y += v.y; acc[j].z += v.z; acc[j].w += v.w;
        }
    }

    // normal-layout bf16 write: 32 contiguous elems per thread (coalesced)
    #pragma unroll
    for (int j = 0; j < 8; j += 2) {
        ushort8 o;
        o[0] = f2bf(acc[j].x);   o[1] = f2bf(acc[j].y);
        o[2] = f2bf(acc[j].z);   o[3] = f2bf(acc[j].w);
        o[4] = f2bf(acc[j+1].x); o[5] = f2bf(acc[j+1].y);
        o[6] = f2bf(acc[j+1].z); o[7] = f2bf(acc[j+1].w);
        *(ushort8*)(dst + j * 4) = o;
    }

    if (do_transpose) {
        #pragma unroll
        for (int j = 0; j < 8; ++j)
            *(float4*)&tile[r][d0 + j * 4] = acc[j];
        __syncthreads();
        // thread t: d = t>>1, koff = (t&1)*32 -> 32 contiguous kfT elems
        const int d    = tid >> 1;
        const int koff = (tid & 1) * 32;
        unsigned short* tdst =
            kfT + ((size_t)(hop * B_ + b) * D_ + d) * LK_ + row0 + koff;
        #pragma unroll
        for (int i0 = 0; i0 < 32; i0 += 8) {
            ushort8 o;
            #pragma unroll
            for (int i = 0; i < 8; ++i) o[i] = f2bf(tile[koff + i0 + i][d]);
            *(ushort8*)(tdst + i0) = o;
        }
    }
}

// ---------------------------------------------------------------------------
// Kernel 2: attention. One block per (b, 16-query tile): 256 blocks, 512 thr.
//   Phase A: att[16][512] = cf_tile @ kf^T via mfma_f32_16x16x32_bf16
//            (A: lane m=lane&15 holds cf row along d; B: lane n=lane&15 holds
//             kf row along d; C/D: col=lane&15, row=quad*4+reg)
//   softmax rows in LDS, Phase B: PV with p re-read in A-layout from LDS and
//   kfT giving contiguous B-fragments; 1/sum folded into hop accumulation.
// ---------------------------------------------------------------------------
__global__ __launch_bounds__(512) void attn_kernel(
    const unsigned short* __restrict__ kf, const unsigned short* __restrict__ kfT,
    const unsigned short* __restrict__ cf, float* __restrict__ out)
{
    constexpr int AS = 516;                  // row stride: %4==0 (b128 align), %32==4 (bank spread)
    __shared__ float att_s[16][AS];          // 33 KB
    __shared__ float red_s[16][32];
    __shared__ float rowmax_s[16];
    __shared__ float rowinv_s[16];

    const int tid  = threadIdx.x;
    const int wave = tid >> 6;               // 0..7
    const int lane = tid & 63;
    const int quad = lane >> 4;              // 0..3
    const int l16  = lane & 15;

    const int b  = blockIdx.x >> 4;
    const int l0 = (blockIdx.x & 15) * 16;

    const int srow = tid >> 5;               // softmax row (16 rows x 32 thr)
    const int sc   = tid & 31;

    float out_acc[4] = {0.f, 0.f, 0.f, 0.f}; // rows quad*4+r, col d=wave*16+l16

    for (int hop = 0; hop < 3; ++hop) {
        const unsigned short* cf_h  = cf  + (((size_t)(hop * 16 + b)) * 256 + l0) * 128;
        const unsigned short* kf_h  = kf  + ((size_t)(hop * 16 + b)) * 512 * 128;
        const unsigned short* kfT_h = kfT + ((size_t)(hop * 16 + b)) * 128 * 512;

        // A-fragments (cf rows), reused across all 32 n-tiles
        ushort8 afrag[4];
        #pragma unroll
        for (int ks = 0; ks < 4; ++ks)
            afrag[ks] = *(const ushort8*)(cf_h + l16 * 128 + ks * 32 + quad * 8);

        // -------- Phase A: att = cf @ kf^T --------
        #pragma unroll
        for (int t = 0; t < 4; ++t) {
            const int nt = wave * 4 + t;     // 8 waves x 4 = 32 n-tiles (512 k)
            floatx4 acc = {0.f, 0.f, 0.f, 0.f};
            #pragma unroll
            for (int ks = 0; ks < 4; ++ks) {
                ushort8 bfrag = *(const ushort8*)(kf_h + (nt * 16 + l16) * 128 + ks * 32 + quad * 8);
                acc = mfma_bf16(afrag[ks], bfrag, acc);
            }
            #pragma unroll
            for (int rr = 0; rr < 4; ++rr)
                att_s[quad * 4 + rr][nt * 16 + l16] = acc[rr];
        }
        __syncthreads();

        // -------- softmax over rows of 512 --------
        float mx = -1e30f;
        #pragma unroll
        for (int j = 0; j < 16; ++j) mx = fmaxf(mx, att_s[srow][sc + j * 32]);
        red_s[srow][sc] = mx;
        __syncthreads();
        if (tid < 16) {
            float mm = red_s[tid][0];
            for (int i = 1; i < 32; ++i) mm = fmaxf(mm, red_s[tid][i]);
            rowmax_s[tid] = mm;
        }
        __syncthreads();
        const float mm = rowmax_s[srow];
        float sum = 0.f;
        #pragma unroll
        for (int j = 0; j < 16; ++j) {
            float e = __expf(att_s[srow][sc + j * 32] - mm);
            att_s[srow][sc + j * 32] = e;
            sum += e;
        }
        red_s[srow][sc] = sum;
        __syncthreads();
        if (tid < 16) {
            float ss = 0.f;
            for (int i = 0; i < 32; ++i) ss += red_s[tid][i];
            rowinv_s[tid] = 1.0f / ss;
        }
        __syncthreads();

        // -------- Phase B: out_tile = p @ kf  (wave owns d-tile = wave) ----
        floatx4 pacc = {0.f, 0.f, 0.f, 0.f};
        #pragma unroll
        for (int ks = 0; ks < 16; ++ks) {
            const float* prow = &att_s[l16][ks * 32 + quad * 8];
            float4 p0 = *(const float4*)(prow);
            float4 p1 = *(const float4*)(prow + 4);
            ushort8 pa;
            pa[0] = f2bf(p0.x); pa[1] = f2bf(p0.y); pa[2] = f2bf(p0.z); pa[3] = f2bf(p0.w);
            pa[4] = f2bf(p1.x); pa[5] = f2bf(p1.y); pa[6] = f2bf(p1.z); pa[7] = f2bf(p1.w);
            ushort8 bfrag = *(const ushort8*)(kfT_h + (size_t)(wave * 16 + l16) * 512 + ks * 32 + quad * 8);
            pacc = mfma_bf16(pa, bfrag, pacc);
        }
        #pragma unroll
        for (int rr = 0; rr < 4; ++rr)
            out_acc[rr] += pacc[rr] * rowinv_s[quad * 4 + rr];
        __syncthreads();                     // att_s / rowinv_s reused next hop
    }

    // out layout: [Lc, B, D]
    const int d = wave * 16 + l16;
    #pragma unroll
    for (int rr = 0; rr < 4; ++rr)
        out[(((size_t)(l0 + quad * 4 + rr)) * 16 + b) * 128 + d] = out_acc[rr];
}

extern "C" void kernel_launch(void* const* d_in, const int* in_sizes, int n_in,
                              void* d_out, int out_size, void* d_ws, size_t ws_size,
                              hipStream_t stream) {
    (void)in_sizes; (void)n_in; (void)out_size; (void)ws_size;
    const int*   conv_seqs = (const int*)d_in[0];
    const int*   kb_arr    = (const int*)d_in[1];
    const float* C         = (const float*)d_in[2];
    const float* K         = (const float*)d_in[3];

    // ws layout (bf16): kf [3][16][512][128], kfT [3][16][128][512], cf [3][16][256][128]
    unsigned short* kf  = (unsigned short*)d_ws;
    unsigned short* kfT = kf  + (size_t)HOPS_ * B_ * LK_ * D_;
    unsigned short* cf  = kfT + (size_t)HOPS_ * B_ * LK_ * D_;
    float* out = (float*)d_out;

    hipLaunchKernelGGL(gather_kernel, dim3(576), dim3(256), 0, stream,
                       conv_seqs, kb_arr, C, K, kf, kfT, cf);
    hipLaunchKernelGGL(attn_kernel, dim3(256), dim3(512), 0, stream,
                       kf, kfT, cf, out);
}

// Round 2
// 198.563 us; speedup vs baseline: 1.3236x; 1.3236x over previous
//
#include <hip/hip_runtime.h>

// Problem constants (from setup_inputs)
#define V_    50000
#define D_    128
#define HOPS_ 3
#define B_    16
#define LC_   256
#define MC_   8
#define LK_   512
#define MK_   8

typedef __bf16  bf16x8  __attribute__((ext_vector_type(8)));
typedef unsigned short ushort8 __attribute__((ext_vector_type(8)));
typedef float   floatx4 __attribute__((ext_vector_type(4)));

__device__ inline unsigned short f2bf(float f) {
    union { float f; unsigned u; } x; x.f = f;
    unsigned r = x.u + 0x7FFFu + ((x.u >> 16) & 1u);   // RNE
    return (unsigned short)(r >> 16);
}

__device__ inline floatx4 mfma_bf16(ushort8 a, ushort8 b, floatx4 c) {
    return __builtin_amdgcn_mfma_f32_16x16x32_bf16(
        __builtin_bit_cast(bf16x8, a), __builtin_bit_cast(bf16x8, b), c, 0, 0, 0);
}

// ---------------------------------------------------------------------------
// Kernel 0: zero the output (harness poisons d_out with 0xAA; attn uses atomics)
// ---------------------------------------------------------------------------
__global__ __launch_bounds__(256) void zero_kernel(float4* __restrict__ p) {
    p[(size_t)blockIdx.x * 256 + threadIdx.x] = make_float4(0.f, 0.f, 0.f, 0.f);
}

// ---------------------------------------------------------------------------
// Kernel 1: embedding-bag gathers. 32-row tiles for MLP (1152 blocks,
// 18 waves/CU). Thread owns (row = tid>>3, 16-float seg = tid&7); the 8 lanes
// of a row read one contiguous 512B table row per index. Index loaded once
// per lane, broadcast via __shfl.
//   blocks [0,768):    kf tiles (hop,b,ktile) + transposed copy -> kfT
//   blocks [768,1152): cf tiles (hop,b,ltile)
// ---------------------------------------------------------------------------
__global__ __launch_bounds__(256) void gather_kernel(
    const int* __restrict__ conv_seqs, const int* __restrict__ kb_arr,
    const float* __restrict__ Ct, const float* __restrict__ Kt,
    unsigned short* __restrict__ kf, unsigned short* __restrict__ kfT,
    unsigned short* __restrict__ cf)
{
    __shared__ float tile[32][132];          // +4 pad: conflict-free transpose

    const int tid  = threadIdx.x;
    const int r    = tid >> 3;               // row in tile (0..31)
    const int s    = tid & 7;                // 16-float segment
    const int d0   = s * 16;
    const int lane = tid & 63;
    const int bx   = blockIdx.x;

    const int*   idxp;
    const float* table;
    unsigned short* dst;
    bool do_transpose;
    int hop, b, row0;

    constexpr int KBLK = HOPS_ * B_ * (LK_ / 32);   // 768
    if (bx < KBLK) {
        hop  = bx / (B_ * 16);
        int rem = bx % (B_ * 16);
        b    = rem >> 4;
        row0 = (rem & 15) * 32;
        idxp  = kb_arr + (size_t)(b * LK_ + row0 + r) * MK_;
        table = Kt + (size_t)hop * V_ * D_;
        dst   = kf + (((size_t)(hop * B_ + b) * LK_) + row0 + r) * D_ + d0;
        do_transpose = true;
    } else {
        int id = bx - KBLK;
        hop  = id / (B_ * 8);
        int rem = id % (B_ * 8);
        b    = rem >> 3;
        row0 = (rem & 7) * 32;
        idxp  = conv_seqs + (size_t)(b * LC_ + row0 + r) * MC_;
        table = Ct + (size_t)hop * V_ * D_;
        dst   = cf + (((size_t)(hop * B_ + b) * LC_) + row0 + r) * D_ + d0;
        do_transpose = false;
    }

    const int myidx = idxp[s];               // one idx per lane, coalesced 32B/row

    float4 acc[4];
    #pragma unroll
    for (int j = 0; j < 4; ++j) acc[j] = make_float4(0.f, 0.f, 0.f, 0.f);

    #pragma unroll
    for (int m = 0; m < 8; ++m) {
        int idx = __shfl(myidx, (lane & 56) + m);    // broadcast within row group
        const float4* src = (const float4*)(table + (size_t)idx * D_ + d0);
        #pragma unroll
        for (int j = 0; j < 4; ++j) {
            float4 v = src[j];
            acc[j].x += v.x; acc[j].y += v.y; acc[j].z += v.z; acc[j].w += v.w;
        }
    }

    // normal-layout bf16 write: 16 contiguous elems (32B) per thread, coalesced
    {
        ushort8 o0, o1;
        o0[0] = f2bf(acc[0].x); o0[1] = f2bf(acc[0].y);
        o0[2] = f2bf(acc[0].z); o0[3] = f2bf(acc[0].w);
        o0[4] = f2bf(acc[1].x); o0[5] = f2bf(acc[1].y);
        o0[6] = f2bf(acc[1].z); o0[7] = f2bf(acc[1].w);
        o1[0] = f2bf(acc[2].x); o1[1] = f2bf(acc[2].y);
        o1[2] = f2bf(acc[2].z); o1[3] = f2bf(acc[2].w);
        o1[4] = f2bf(acc[3].x); o1[5] = f2bf(acc[3].y);
        o1[6] = f2bf(acc[3].z); o1[7] = f2bf(acc[3].w);
        *(ushort8*)(dst)     = o0;
        *(ushort8*)(dst + 8) = o1;
    }

    if (do_transpose) {
        #pragma unroll
        for (int j = 0; j < 4; ++j)
            *(float4*)&tile[r][d0 + j * 4] = acc[j];
        __syncthreads();
        // thread t: d = t>>1, koff = (t&1)*16 -> 16 contiguous kfT elems (32B);
        // even/odd thread pairs merge into 64B segments
        const int d    = tid >> 1;
        const int koff = (tid & 1) * 16;
        unsigned short* tdst =
            kfT + ((size_t)(hop * B_ + b) * D_ + d) * LK_ + row0 + koff;
        #pragma unroll
        for (int i0 = 0; i0 < 16; i0 += 8) {
            ushort8 o;
            #pragma unroll
            for (int i = 0; i < 8; ++i) o[i] = f2bf(tile[koff + i0 + i][d]);
            *(ushort8*)(tdst + i0) = o;
        }
    }
}

// ---------------------------------------------------------------------------
// Kernel 2: attention, hop-parallel. One block per (hop, b, 16-query tile):
// 768 blocks x 512 thr (3 blocks/CU, 24 waves/CU).
//   Phase A: att[16][512] = cf_tile @ kf^T via mfma_f32_16x16x32_bf16
//   softmax: per-wave shuffle butterfly, 2 rows/wave (no serial loops)
//   Phase B: p @ kf via LDS round-trip for A-layout; kfT gives contiguous
//            B-fragments. 1/sum folded in; hop-sum via fp32 atomicAdd.
// Only 2 barriers per block.
// ---------------------------------------------------------------------------
__global__ __launch_bounds__(512) void attn_kernel(
    const unsigned short* __restrict__ kf, const unsigned short* __restrict__ kfT,
    const unsigned short* __restrict__ cf, float* __restrict__ out)
{
    constexpr int AS = 516;                  // row stride: %4==0 (b128 align), %32==4 (bank spread)
    __shared__ float att_s[16][AS];          // 33 KB
    __shared__ float rowinv_s[16];

    const int tid  = threadIdx.x;
    const int wave = tid >> 6;               // 0..7
    const int lane = tid & 63;
    const int quad = lane >> 4;              // 0..3
    const int l16  = lane & 15;

    const int hop = blockIdx.x >> 8;         // 0..2
    const int rem = blockIdx.x & 255;
    const int b   = rem >> 4;
    const int l0  = (rem & 15) * 16;

    const unsigned short* cf_h  = cf  + (((size_t)(hop * 16 + b)) * 256 + l0) * 128;
    const unsigned short* kf_h  = kf  + ((size_t)(hop * 16 + b)) * 512 * 128;
    const unsigned short* kfT_h = kfT + ((size_t)(hop * 16 + b)) * 128 * 512;

    // A-fragments (cf rows), reused across all 32 n-tiles
    ushort8 afrag[4];
    #pragma unroll
    for (int ks = 0; ks < 4; ++ks)
        afrag[ks] = *(const ushort8*)(cf_h + l16 * 128 + ks * 32 + quad * 8);

    // -------- Phase A: att = cf @ kf^T --------
    #pragma unroll
    for (int t = 0; t < 4; ++t) {
        const int nt = wave * 4 + t;         // 8 waves x 4 = 32 n-tiles (512 k)
        floatx4 acc = {0.f, 0.f, 0.f, 0.f};
        #pragma unroll
        for (int ks = 0; ks < 4; ++ks) {
            ushort8 bfrag = *(const ushort8*)(kf_h + (nt * 16 + l16) * 128 + ks * 32 + quad * 8);
            acc = mfma_bf16(afrag[ks], bfrag, acc);
        }
        #pragma unroll
        for (int rr = 0; rr < 4; ++rr)
            att_s[quad * 4 + rr][nt * 16 + l16] = acc[rr];
    }
    __syncthreads();

    // -------- softmax: wave handles rows 2*wave, 2*wave+1 --------
    #pragma unroll
    for (int rr = 0; rr < 2; ++rr) {
        const int row = wave * 2 + rr;
        float v[8];
        float mx = -1e30f;
        #pragma unroll
        for (int j = 0; j < 8; ++j) {
            v[j] = att_s[row][lane + j * 64];
            mx = fmaxf(mx, v[j]);
        }
        #pragma unroll
        for (int off = 32; off; off >>= 1) mx = fmaxf(mx, __shfl_xor(mx, off));
        float sum = 0.f;
        #pragma unroll
        for (int j = 0; j < 8; ++j) {
            float e = __expf(v[j] - mx);
            att_s[row][lane + j * 64] = e;
            sum += e;
        }
        #pragma unroll
        for (int off = 32; off; off >>= 1) sum += __shfl_xor(sum, off);
        if (lane == 0) rowinv_s[row] = 1.0f / sum;
    }
    __syncthreads();

    // -------- Phase B: out_tile = p @ kf  (wave owns d-tile = wave) --------
    floatx4 pacc = {0.f, 0.f, 0.f, 0.f};
    #pragma unroll
    for (int ks = 0; ks < 16; ++ks) {
        const float* prow = &att_s[l16][ks * 32 + quad * 8];
        float4 p0 = *(const float4*)(prow);
        float4 p1 = *(const float4*)(prow + 4);
        ushort8 pa;
        pa[0] = f2bf(p0.x); pa[1] = f2bf(p0.y); pa[2] = f2bf(p0.z); pa[3] = f2bf(p0.w);
        pa[4] = f2bf(p1.x); pa[5] = f2bf(p1.y); pa[6] = f2bf(p1.z); pa[7] = f2bf(p1.w);
        ushort8 bfrag = *(const ushort8*)(kfT_h + (size_t)(wave * 16 + l16) * 512 + ks * 32 + quad * 8);
        pacc = mfma_bf16(pa, bfrag, pacc);
    }

    // out layout: [Lc, B, D]; hop-sum via atomics
    const int d = wave * 16 + l16;
    #pragma unroll
    for (int rr = 0; rr < 4; ++rr)
        atomicAdd(&out[(((size_t)(l0 + quad * 4 + rr)) * 16 + b) * 128 + d],
                  pacc[rr] * rowinv_s[quad * 4 + rr]);
}

extern "C" void kernel_launch(void* const* d_in, const int* in_sizes, int n_in,
                              void* d_out, int out_size, void* d_ws, size_t ws_size,
                              hipStream_t stream) {
    (void)in_sizes; (void)n_in; (void)out_size; (void)ws_size;
    const int*   conv_seqs = (const int*)d_in[0];
    const int*   kb_arr    = (const int*)d_in[1];
    const float* C         = (const float*)d_in[2];
    const float* K         = (const float*)d_in[3];

    // ws layout (bf16): kf [3][16][512][128], kfT [3][16][128][512], cf [3][16][256][128]
    unsigned short* kf  = (unsigned short*)d_ws;
    unsigned short* kfT = kf  + (size_t)HOPS_ * B_ * LK_ * D_;
    unsigned short* cf  = kfT + (size_t)HOPS_ * B_ * LK_ * D_;
    float* out = (float*)d_out;

    // out = 256*16*128 = 524288 floats = 131072 float4 = 512 blocks * 256 thr
    hipLaunchKernelGGL(zero_kernel, dim3(512), dim3(256), 0, stream, (float4*)out);
    hipLaunchKernelGGL(gather_kernel, dim3(1152), dim3(256), 0, stream,
                       conv_seqs, kb_arr, C, K, kf, kfT, cf);
    hipLaunchKernelGGL(attn_kernel, dim3(768), dim3(512), 0, stream,
                       kf, kfT, cf, out);
}

// Round 3
// 195.951 us; speedup vs baseline: 1.3413x; 1.0133x over previous
//
#include <hip/hip_runtime.h>

// Problem constants (from setup_inputs)
#define V_    50000
#define D_    128
#define HOPS_ 3
#define B_    16
#define LC_   256
#define MC_   8
#define LK_   512
#define MK_   8

typedef __bf16  bf16x8  __attribute__((ext_vector_type(8)));
typedef unsigned short ushort8 __attribute__((ext_vector_type(8)));
typedef float   floatx4 __attribute__((ext_vector_type(4)));

__device__ inline unsigned short f2bf(float f) {
    union { float f; unsigned u; } x; x.f = f;
    unsigned r = x.u + 0x7FFFu + ((x.u >> 16) & 1u);   // RNE
    return (unsigned short)(r >> 16);
}

__device__ inline floatx4 mfma_bf16(ushort8 a, ushort8 b, floatx4 c) {
    return __builtin_amdgcn_mfma_f32_16x16x32_bf16(
        __builtin_bit_cast(bf16x8, a), __builtin_bit_cast(bf16x8, b), c, 0, 0, 0);
}

// ---------------------------------------------------------------------------
// Kernel 1: embedding-bag gathers (+ output zeroing in tail blocks).
// 32-row tiles for MLP. Thread owns (row = tid>>3, 16-float seg = tid&7);
// the 8 lanes of a row read one contiguous 512B table row per index.
//   blocks [0,768):      kf tiles (hop,b,ktile) + transposed copy -> kfT
//   blocks [768,1152):   cf tiles (hop,b,ltile)
//   blocks [1152,1664):  zero d_out (512 blocks x 256 thr x float4)
// ---------------------------------------------------------------------------
__global__ __launch_bounds__(256) void gather_kernel(
    const int* __restrict__ conv_seqs, const int* __restrict__ kb_arr,
    const float* __restrict__ Ct, const float* __restrict__ Kt,
    unsigned short* __restrict__ kf, unsigned short* __restrict__ kfT,
    unsigned short* __restrict__ cf, float4* __restrict__ out4)
{
    __shared__ float tile[32][132];          // +4 pad: conflict-free transpose

    const int tid  = threadIdx.x;
    const int bx   = blockIdx.x;

    constexpr int KBLK = HOPS_ * B_ * (LK_ / 32);   // 768
    constexpr int CBLK = HOPS_ * B_ * (LC_ / 32);   // 384

    if (bx >= KBLK + CBLK) {                 // zero-out blocks
        int zb = bx - (KBLK + CBLK);
        out4[(size_t)zb * 256 + tid] = make_float4(0.f, 0.f, 0.f, 0.f);
        return;
    }

    const int r    = tid >> 3;               // row in tile (0..31)
    const int s    = tid & 7;                // 16-float segment
    const int d0   = s * 16;
    const int lane = tid & 63;

    const int*   idxp;
    const float* table;
    unsigned short* dst;
    bool do_transpose;
    int hop, b, row0;

    if (bx < KBLK) {
        hop  = bx / (B_ * 16);
        int rem = bx % (B_ * 16);
        b    = rem >> 4;
        row0 = (rem & 15) * 32;
        idxp  = kb_arr + (size_t)(b * LK_ + row0 + r) * MK_;
        table = Kt + (size_t)hop * V_ * D_;
        dst   = kf + (((size_t)(hop * B_ + b) * LK_) + row0 + r) * D_ + d0;
        do_transpose = true;
    } else {
        int id = bx - KBLK;
        hop  = id / (B_ * 8);
        int rem = id % (B_ * 8);
        b    = rem >> 3;
        row0 = (rem & 7) * 32;
        idxp  = conv_seqs + (size_t)(b * LC_ + row0 + r) * MC_;
        table = Ct + (size_t)hop * V_ * D_;
        dst   = cf + (((size_t)(hop * B_ + b) * LC_) + row0 + r) * D_ + d0;
        do_transpose = false;
    }

    const int myidx = idxp[s];               // one idx per lane, coalesced 32B/row

    float4 acc[4];
    #pragma unroll
    for (int j = 0; j < 4; ++j) acc[j] = make_float4(0.f, 0.f, 0.f, 0.f);

    #pragma unroll
    for (int m = 0; m < 8; ++m) {
        int idx = __shfl(myidx, (lane & 56) + m);    // broadcast within row group
        const float4* src = (const float4*)(table + (size_t)idx * D_ + d0);
        #pragma unroll
        for (int j = 0; j < 4; ++j) {
            float4 v = src[j];
            acc[j].x += v.x; acc[j].y += v.y; acc[j].z += v.z; acc[j].w += v.w;
        }
    }

    // normal-layout bf16 write: 16 contiguous elems (32B) per thread, coalesced
    {
        ushort8 o0, o1;
        o0[0] = f2bf(acc[0].x); o0[1] = f2bf(acc[0].y);
        o0[2] = f2bf(acc[0].z); o0[3] = f2bf(acc[0].w);
        o0[4] = f2bf(acc[1].x); o0[5] = f2bf(acc[1].y);
        o0[6] = f2bf(acc[1].z); o0[7] = f2bf(acc[1].w);
        o1[0] = f2bf(acc[2].x); o1[1] = f2bf(acc[2].y);
        o1[2] = f2bf(acc[2].z); o1[3] = f2bf(acc[2].w);
        o1[4] = f2bf(acc[3].x); o1[5] = f2bf(acc[3].y);
        o1[6] = f2bf(acc[3].z); o1[7] = f2bf(acc[3].w);
        *(ushort8*)(dst)     = o0;
        *(ushort8*)(dst + 8) = o1;
    }

    if (do_transpose) {
        #pragma unroll
        for (int j = 0; j < 4; ++j)
            *(float4*)&tile[r][d0 + j * 4] = acc[j];
        __syncthreads();
        const int d    = tid >> 1;
        const int koff = (tid & 1) * 16;
        unsigned short* tdst =
            kfT + ((size_t)(hop * B_ + b) * D_ + d) * LK_ + row0 + koff;
        #pragma unroll
        for (int i0 = 0; i0 < 16; i0 += 8) {
            ushort8 o;
            #pragma unroll
            for (int i = 0; i < 8; ++i) o[i] = f2bf(tile[koff + i0 + i][d]);
            *(ushort8*)(tdst + i0) = o;
        }
    }
}

// ---------------------------------------------------------------------------
// Kernel 2: attention, hop-parallel, XCD-swizzled. One block per
// (hop, b, 16-query tile): 768 blocks x 512 thr (3 blocks/CU).
// Swizzle: all 16 l-tile blocks of one (hop,b) group share bx%8 -> same XCD
// (round-robin dispatch), so kf/kfT (256 KB/group) is served by that XCD's
// 4MB L2 after the first block pulls it (6 groups/XCD = 1.5 MB resident).
//   bx = ((lt*6 + g/8) << 3) | (g%8),  g = hop*16+b
//   Phase A: att[16][512] = cf_tile @ kf^T via mfma_f32_16x16x32_bf16
//   softmax: per-wave shuffle butterfly, 2 rows/wave
//   Phase B: p @ kf via LDS round-trip (A-layout) with kfT B-fragments;
//            1/sum folded in; hop-sum via fp32 atomicAdd. 2 barriers total.
// ---------------------------------------------------------------------------
__global__ __launch_bounds__(512) void attn_kernel(
    const unsigned short* __restrict__ kf, const unsigned short* __restrict__ kfT,
    const unsigned short* __restrict__ cf, float* __restrict__ out)
{
    constexpr int AS = 516;                  // row stride: %4==0 (b128 align), %32==4 (bank spread)
    __shared__ float att_s[16][AS];          // 33 KB
    __shared__ float rowinv_s[16];

    const int tid  = threadIdx.x;
    const int wave = tid >> 6;               // 0..7
    const int lane = tid & 63;
    const int quad = lane >> 4;              // 0..3
    const int l16  = lane & 15;

    // XCD-swizzle decode
    const int gl  = blockIdx.x & 7;
    const int s_  = blockIdx.x >> 3;         // 0..95
    const int lt  = s_ / 6;                  // 0..15
    const int gh  = s_ % 6;                  // 0..5
    const int g   = gh * 8 + gl;             // 0..47 = hop*16+b
    const int hop = g >> 4;
    const int b   = g & 15;
    const int l0  = lt * 16;

    const unsigned short* cf_h  = cf  + (((size_t)g) * 256 + l0) * 128;
    const unsigned short* kf_h  = kf  + ((size_t)g) * 512 * 128;
    const unsigned short* kfT_h = kfT + ((size_t)g) * 128 * 512;

    // A-fragments (cf rows), reused across all 32 n-tiles
    ushort8 afrag[4];
    #pragma unroll
    for (int ks = 0; ks < 4; ++ks)
        afrag[ks] = *(const ushort8*)(cf_h + l16 * 128 + ks * 32 + quad * 8);

    // -------- Phase A: att = cf @ kf^T --------
    #pragma unroll
    for (int t = 0; t < 4; ++t) {
        const int nt = wave * 4 + t;         // 8 waves x 4 = 32 n-tiles (512 k)
        floatx4 acc = {0.f, 0.f, 0.f, 0.f};
        #pragma unroll
        for (int ks = 0; ks < 4; ++ks) {
            ushort8 bfrag = *(const ushort8*)(kf_h + (nt * 16 + l16) * 128 + ks * 32 + quad * 8);
            acc = mfma_bf16(afrag[ks], bfrag, acc);
        }
        #pragma unroll
        for (int rr = 0; rr < 4; ++rr)
            att_s[quad * 4 + rr][nt * 16 + l16] = acc[rr];
    }
    __syncthreads();

    // -------- softmax: wave handles rows 2*wave, 2*wave+1 --------
    #pragma unroll
    for (int rr = 0; rr < 2; ++rr) {
        const int row = wave * 2 + rr;
        float v[8];
        float mx = -1e30f;
        #pragma unroll
        for (int j = 0; j < 8; ++j) {
            v[j] = att_s[row][lane + j * 64];
            mx = fmaxf(mx, v[j]);
        }
        #pragma unroll
        for (int off = 32; off; off >>= 1) mx = fmaxf(mx, __shfl_xor(mx, off));
        float sum = 0.f;
        #pragma unroll
        for (int j = 0; j < 8; ++j) {
            float e = __expf(v[j] - mx);
            att_s[row][lane + j * 64] = e;
            sum += e;
        }
        #pragma unroll
        for (int off = 32; off; off >>= 1) sum += __shfl_xor(sum, off);
        if (lane == 0) rowinv_s[row] = 1.0f / sum;
    }
    __syncthreads();

    // -------- Phase B: out_tile = p @ kf  (wave owns d-tile = wave) --------
    floatx4 pacc = {0.f, 0.f, 0.f, 0.f};
    #pragma unroll
    for (int ks = 0; ks < 16; ++ks) {
        const float* prow = &att_s[l16][ks * 32 + quad * 8];
        float4 p0 = *(const float4*)(prow);
        float4 p1 = *(const float4*)(prow + 4);
        ushort8 pa;
        pa[0] = f2bf(p0.x); pa[1] = f2bf(p0.y); pa[2] = f2bf(p0.z); pa[3] = f2bf(p0.w);
        pa[4] = f2bf(p1.x); pa[5] = f2bf(p1.y); pa[6] = f2bf(p1.z); pa[7] = f2bf(p1.w);
        ushort8 bfrag = *(const ushort8*)(kfT_h + (size_t)(wave * 16 + l16) * 512 + ks * 32 + quad * 8);
        pacc = mfma_bf16(pa, bfrag, pacc);
    }

    // out layout: [Lc, B, D]; hop-sum via atomics
    const int d = wave * 16 + l16;
    #pragma unroll
    for (int rr = 0; rr < 4; ++rr)
        atomicAdd(&out[(((size_t)(l0 + quad * 4 + rr)) * 16 + b) * 128 + d],
                  pacc[rr] * rowinv_s[quad * 4 + rr]);
}

extern "C" void kernel_launch(void* const* d_in, const int* in_sizes, int n_in,
                              void* d_out, int out_size, void* d_ws, size_t ws_size,
                              hipStream_t stream) {
    (void)in_sizes; (void)n_in; (void)out_size; (void)ws_size;
    const int*   conv_seqs = (const int*)d_in[0];
    const int*   kb_arr    = (const int*)d_in[1];
    const float* C         = (const float*)d_in[2];
    const float* K         = (const float*)d_in[3];

    // ws layout (bf16): kf [3][16][512][128], kfT [3][16][128][512], cf [3][16][256][128]
    unsigned short* kf  = (unsigned short*)d_ws;
    unsigned short* kfT = kf  + (size_t)HOPS_ * B_ * LK_ * D_;
    unsigned short* cf  = kfT + (size_t)HOPS_ * B_ * LK_ * D_;
    float* out = (float*)d_out;

    // gather grid: 768 kf + 384 cf + 512 zero-out blocks
    hipLaunchKernelGGL(gather_kernel, dim3(1664), dim3(256), 0, stream,
                       conv_seqs, kb_arr, C, K, kf, kfT, cf, (float4*)out);
    hipLaunchKernelGGL(attn_kernel, dim3(768), dim3(512), 0, stream,
                       kf, kfT, cf, out);
}

// Round 4
// 194.220 us; speedup vs baseline: 1.3532x; 1.0089x over previous
//
#include <hip/hip_runtime.h>

// Problem constants (from setup_inputs)
#define V_    50000
#define D_    128
#define HOPS_ 3
#define B_    16
#define LC_   256
#define MC_   8
#define LK_   512
#define MK_   8

typedef __bf16  bf16x8  __attribute__((ext_vector_type(8)));
typedef unsigned short ushort8 __attribute__((ext_vector_type(8)));
typedef unsigned short ushort4v __attribute__((ext_vector_type(4)));
typedef float   floatx4 __attribute__((ext_vector_type(4)));

__device__ inline unsigned short f2bf(float f) {
    union { float f; unsigned u; } x; x.f = f;
    unsigned r = x.u + 0x7FFFu + ((x.u >> 16) & 1u);   // RNE
    return (unsigned short)(r >> 16);
}

__device__ inline floatx4 mfma_bf16(ushort8 a, ushort8 b, floatx4 c) {
    return __builtin_amdgcn_mfma_f32_16x16x32_bf16(
        __builtin_bit_cast(bf16x8, a), __builtin_bit_cast(bf16x8, b), c, 0, 0, 0);
}

// ---------------------------------------------------------------------------
// Kernel 1: embedding-bag gathers. NO LDS (kfT moved out) -> 7 blocks/CU.
// Thread owns (row = tid>>3, s = tid&7); load j covers row bytes
// [j*128, j*128+128) contiguously across the 8-lane cluster (2 cache lines
// per cluster per instruction instead of 8).
//   blocks [0,768):    kf tiles (hop,b,ktile of 32 rows)
//   blocks [768,1152): cf tiles (hop,b,ltile of 32 rows)
// ---------------------------------------------------------------------------
__global__ __launch_bounds__(256, 7) void gather_kernel(
    const int* __restrict__ conv_seqs, const int* __restrict__ kb_arr,
    const float* __restrict__ Ct, const float* __restrict__ Kt,
    unsigned short* __restrict__ kf, unsigned short* __restrict__ cf)
{
    const int tid  = threadIdx.x;
    const int r    = tid >> 3;               // row in tile (0..31)
    const int s    = tid & 7;                // position within 8-lane cluster
    const int lane = tid & 63;
    const int bx   = blockIdx.x;

    constexpr int KBLK = HOPS_ * B_ * (LK_ / 32);   // 768

    const int*   idxp;
    const float* table;
    unsigned short* dst;                     // row base (element 0)

    if (bx < KBLK) {
        int hop  = bx / (B_ * 16);
        int rem  = bx % (B_ * 16);
        int b    = rem >> 4;
        int row0 = (rem & 15) * 32;
        idxp  = kb_arr + (size_t)(b * LK_ + row0 + r) * MK_;
        table = Kt + (size_t)hop * V_ * D_;
        dst   = kf + (((size_t)(hop * B_ + b) * LK_) + row0 + r) * D_;
    } else {
        int id   = bx - KBLK;
        int hop  = id / (B_ * 8);
        int rem  = id % (B_ * 8);
        int b    = rem >> 3;
        int row0 = (rem & 7) * 32;
        idxp  = conv_seqs + (size_t)(b * LC_ + row0 + r) * MC_;
        table = Ct + (size_t)hop * V_ * D_;
        dst   = cf + (((size_t)(hop * B_ + b) * LC_) + row0 + r) * D_;
    }

    const int myidx = idxp[s];               // one idx per lane, coalesced
    int idxs[8];
    #pragma unroll
    for (int m = 0; m < 8; ++m)
        idxs[m] = __shfl(myidx, (lane & 56) + m);

    float4 acc[4];
    #pragma unroll
    for (int j = 0; j < 4; ++j) acc[j] = make_float4(0.f, 0.f, 0.f, 0.f);

    #pragma unroll
    for (int m = 0; m < 8; ++m) {
        const float* rowp = table + (size_t)idxs[m] * D_;
        #pragma unroll
        for (int j = 0; j < 4; ++j) {
            float4 v = *(const float4*)(rowp + j * 32 + s * 4);
            acc[j].x += v.x; acc[j].y += v.y; acc[j].z += v.z; acc[j].w += v.w;
        }
    }

    // write: thread owns d in {j*32 + s*4 .. +4}; 8B/lane, cluster-contiguous
    #pragma unroll
    for (int j = 0; j < 4; ++j) {
        ushort4v o;
        o[0] = f2bf(acc[j].x); o[1] = f2bf(acc[j].y);
        o[2] = f2bf(acc[j].z); o[3] = f2bf(acc[j].w);
        *(ushort4v*)(dst + j * 32 + s * 4) = o;
    }
}

// ---------------------------------------------------------------------------
// Kernel 1b: kf -> kfT transpose (64x64 bf16 tiles) + zero d_out in tail.
//   blocks [0,768):    transpose: g = bx>>4, dt = (bx&15)>>3, kt = bx&7
//   blocks [768,1280): zero d_out (float4)
// ---------------------------------------------------------------------------
__global__ __launch_bounds__(256) void transpose_kernel(
    const unsigned short* __restrict__ kf, unsigned short* __restrict__ kfT,
    float4* __restrict__ out4)
{
    __shared__ unsigned short tile[64][72];  // stride 144B: 16B-aligned rows

    const int tid = threadIdx.x;
    const int bx  = blockIdx.x;

    if (bx >= 768) {
        out4[(size_t)(bx - 768) * 256 + tid] = make_float4(0.f, 0.f, 0.f, 0.f);
        return;
    }

    const int g  = bx >> 4;                  // 0..47 = hop*16+b
    const int dt = (bx & 15) >> 3;           // 0..1
    const int kt = bx & 7;                   // 0..7
    const int k0 = kt * 64, d0 = dt * 64;

    const int r = tid >> 2;                  // 0..63
    const int c = tid & 3;                   // 0..3

    const unsigned short* src = kf + ((size_t)g * 512 + k0 + r) * 128 + d0 + c * 16;
    ushort8 a = *(const ushort8*)(src);
    ushort8 b = *(const ushort8*)(src + 8);
    *(ushort8*)&tile[r][c * 16]     = a;
    *(ushort8*)&tile[r][c * 16 + 8] = b;
    __syncthreads();

    unsigned short* dstp = kfT + ((size_t)g * 128 + d0 + r) * 512 + k0 + c * 16;
    ushort8 o0, o1;
    #pragma unroll
    for (int i = 0; i < 8; ++i) o0[i] = tile[c * 16 + i][r];
    #pragma unroll
    for (int i = 0; i < 8; ++i) o1[i] = tile[c * 16 + 8 + i][r];
    *(ushort8*)(dstp)     = o0;
    *(ushort8*)(dstp + 8) = o1;
}

// ---------------------------------------------------------------------------
// Kernel 2: attention, hop-parallel, XCD-swizzled. One block per
// (hop, b, 16-query tile): 768 blocks x 512 thr (3 blocks/CU).
//   bx = ((lt*6 + g/8) << 3) | (g%8),  g = hop*16+b
//   Phase A: att[16][512] = cf_tile @ kf^T via mfma_f32_16x16x32_bf16
//   softmax: per-wave shuffle butterfly, 2 rows/wave
//   Phase B: p @ kf via LDS round-trip (A-layout) with kfT B-fragments;
//            1/sum folded in; hop-sum via fp32 atomicAdd. 2 barriers total.
// ---------------------------------------------------------------------------
__global__ __launch_bounds__(512) void attn_kernel(
    const unsigned short* __restrict__ kf, const unsigned short* __restrict__ kfT,
    const unsigned short* __restrict__ cf, float* __restrict__ out)
{
    constexpr int AS = 516;                  // row stride: %4==0 (b128 align), %32==4 (bank spread)
    __shared__ float att_s[16][AS];          // 33 KB
    __shared__ float rowinv_s[16];

    const int tid  = threadIdx.x;
    const int wave = tid >> 6;               // 0..7
    const int lane = tid & 63;
    const int quad = lane >> 4;              // 0..3
    const int l16  = lane & 15;

    // XCD-swizzle decode
    const int gl  = blockIdx.x & 7;
    const int s_  = blockIdx.x >> 3;         // 0..95
    const int lt  = s_ / 6;                  // 0..15
    const int gh  = s_ % 6;                  // 0..5
    const int g   = gh * 8 + gl;             // 0..47 = hop*16+b
    const int b   = g & 15;
    const int l0  = lt * 16;

    const unsigned short* cf_h  = cf  + (((size_t)g) * 256 + l0) * 128;
    const unsigned short* kf_h  = kf  + ((size_t)g) * 512 * 128;
    const unsigned short* kfT_h = kfT + ((size_t)g) * 128 * 512;

    // A-fragments (cf rows), reused across all 32 n-tiles
    ushort8 afrag[4];
    #pragma unroll
    for (int ks = 0; ks < 4; ++ks)
        afrag[ks] = *(const ushort8*)(cf_h + l16 * 128 + ks * 32 + quad * 8);

    // -------- Phase A: att = cf @ kf^T --------
    #pragma unroll
    for (int t = 0; t < 4; ++t) {
        const int nt = wave * 4 + t;         // 8 waves x 4 = 32 n-tiles (512 k)
        floatx4 acc = {0.f, 0.f, 0.f, 0.f};
        #pragma unroll
        for (int ks = 0; ks < 4; ++ks) {
            ushort8 bfrag = *(const ushort8*)(kf_h + (nt * 16 + l16) * 128 + ks * 32 + quad * 8);
            acc = mfma_bf16(afrag[ks], bfrag, acc);
        }
        #pragma unroll
        for (int rr = 0; rr < 4; ++rr)
            att_s[quad * 4 + rr][nt * 16 + l16] = acc[rr];
    }
    __syncthreads();

    // -------- softmax: wave handles rows 2*wave, 2*wave+1 --------
    #pragma unroll
    for (int rr = 0; rr < 2; ++rr) {
        const int row = wave * 2 + rr;
        float v[8];
        float mx = -1e30f;
        #pragma unroll
        for (int j = 0; j < 8; ++j) {
            v[j] = att_s[row][lane + j * 64];
            mx = fmaxf(mx, v[j]);
        }
        #pragma unroll
        for (int off = 32; off; off >>= 1) mx = fmaxf(mx, __shfl_xor(mx, off));
        float sum = 0.f;
        #pragma unroll
        for (int j = 0; j < 8; ++j) {
            float e = __expf(v[j] - mx);
            att_s[row][lane + j * 64] = e;
            sum += e;
        }
        #pragma unroll
        for (int off = 32; off; off >>= 1) sum += __shfl_xor(sum, off);
        if (lane == 0) rowinv_s[row] = 1.0f / sum;
    }
    __syncthreads();

    // -------- Phase B: out_tile = p @ kf  (wave owns d-tile = wave) --------
    floatx4 pacc = {0.f, 0.f, 0.f, 0.f};
    #pragma unroll
    for (int ks = 0; ks < 16; ++ks) {
        const float* prow = &att_s[l16][ks * 32 + quad * 8];
        float4 p0 = *(const float4*)(prow);
        float4 p1 = *(const float4*)(prow + 4);
        ushort8 pa;
        pa[0] = f2bf(p0.x); pa[1] = f2bf(p0.y); pa[2] = f2bf(p0.z); pa[3] = f2bf(p0.w);
        pa[4] = f2bf(p1.x); pa[5] = f2bf(p1.y); pa[6] = f2bf(p1.z); pa[7] = f2bf(p1.w);
        ushort8 bfrag = *(const ushort8*)(kfT_h + (size_t)(wave * 16 + l16) * 512 + ks * 32 + quad * 8);
        pacc = mfma_bf16(pa, bfrag, pacc);
    }

    // out layout: [Lc, B, D]; hop-sum via atomics
    const int d = wave * 16 + l16;
    #pragma unroll
    for (int rr = 0; rr < 4; ++rr)
        atomicAdd(&out[(((size_t)(l0 + quad * 4 + rr)) * 16 + b) * 128 + d],
                  pacc[rr] * rowinv_s[quad * 4 + rr]);
}

extern "C" void kernel_launch(void* const* d_in, const int* in_sizes, int n_in,
                              void* d_out, int out_size, void* d_ws, size_t ws_size,
                              hipStream_t stream) {
    (void)in_sizes; (void)n_in; (void)out_size; (void)ws_size;
    const int*   conv_seqs = (const int*)d_in[0];
    const int*   kb_arr    = (const int*)d_in[1];
    const float* C         = (const float*)d_in[2];
    const float* K         = (const float*)d_in[3];

    // ws layout (bf16): kf [3][16][512][128], kfT [3][16][128][512], cf [3][16][256][128]
    unsigned short* kf  = (unsigned short*)d_ws;
    unsigned short* kfT = kf  + (size_t)HOPS_ * B_ * LK_ * D_;
    unsigned short* cf  = kfT + (size_t)HOPS_ * B_ * LK_ * D_;
    float* out = (float*)d_out;

    hipLaunchKernelGGL(gather_kernel, dim3(1152), dim3(256), 0, stream,
                       conv_seqs, kb_arr, C, K, kf, cf);
    hipLaunchKernelGGL(transpose_kernel, dim3(1280), dim3(256), 0, stream,
                       kf, kfT, (float4*)out);
    hipLaunchKernelGGL(attn_kernel, dim3(768), dim3(512), 0, stream,
                       kf, kfT, cf, out);
}